// Round 2
// baseline (595.978 us; speedup 1.0000x reference)
//
#include <hip/hip_runtime.h>

// LAM module: out = gamma * (softmax(rowmax(E)-E) @ q) + x,  E = cosine-sim(q,q)
// B=2, N=32, D = 64*128*128 = 1,048,576, all fp32.
//
// Plan:
//  k_zero : zero 8 partial-Gram slots in ws (ws is poisoned each call)
//  k_gram : G[b] = q q^T via bf16 MFMA 32x32x16, A-frag == B-frag (1x read of x)
//  k_attn : tiny 32x32 softmax; M = gamma*attention + I  (folds residual)
//  k_apply: out = M @ q  (1x read + 1x write of x-sized data)

#define NROW 32
static const size_t D_FULL = 1048576ull;   // 64*128*128
#define EPSN 1e-12f

typedef __attribute__((ext_vector_type(8)))  __bf16 bf16x8;
typedef __attribute__((ext_vector_type(16))) float  f32x16;

// ---------------------------------------------------------------- k_zero ----
__global__ __launch_bounds__(256) void k_zero(float* g) {
    // 16 blocks * 256 threads * 1 float4 = 16384 floats (8 slots * 2048)
    int i = blockIdx.x * 256 + threadIdx.x;
    ((float4*)g)[i] = make_float4(0.f, 0.f, 0.f, 0.f);
}

// ---------------------------------------------------------------- k_gram ----
// grid = 512 blocks (256 per batch), block = 256 (4 waves).
// Each wave: 64 MFMA K-steps over 1024 contiguous d-columns.
// Lane l loads q[row = l&31, dbase + (l>>5)*8 + 0..7] as fp32 -> bf16.
// A-frag == B-frag  =>  D = Gram tile (symmetric; layout-detail-proof).
__global__ __launch_bounds__(256) void k_gram(const float* __restrict__ x,
                                              float* __restrict__ gpart) {
    const int tid  = threadIdx.x;
    const int w    = tid >> 6;
    const int lane = tid & 63;
    const int b    = blockIdx.x >> 8;          // 0..1
    const int dblk = (blockIdx.x & 255) << 12; // *4096
    const int row  = lane & 31;
    const int kg   = lane >> 5;                // k-group 0/1 (k = kg*8 + j)

    const float* p = x + ((size_t)(b * NROW + row)) * D_FULL
                       + (size_t)dblk + (size_t)w * 1024 + (size_t)kg * 8;

    f32x16 acc = (f32x16)(0.0f);
    #pragma unroll 4
    for (int it = 0; it < 64; ++it) {
        float4 v0 = *(const float4*)(p);
        float4 v1 = *(const float4*)(p + 4);
        bf16x8 f;
        f[0] = (__bf16)v0.x; f[1] = (__bf16)v0.y;
        f[2] = (__bf16)v0.z; f[3] = (__bf16)v0.w;
        f[4] = (__bf16)v1.x; f[5] = (__bf16)v1.y;
        f[6] = (__bf16)v1.z; f[7] = (__bf16)v1.w;
        acc = __builtin_amdgcn_mfma_f32_32x32x16_bf16(f, f, acc, 0, 0, 0);
        p += 16;
    }

    // C/D layout (verified m74/m101): col = lane&31, row = (r&3)+8*(r>>2)+4*(lane>>5)
    __shared__ float red[4][1024];
    const int col  = lane & 31;
    const int rsel = lane >> 5;
    #pragma unroll
    for (int r = 0; r < 16; ++r) {
        int rw = (r & 3) + 8 * (r >> 2) + 4 * rsel;
        red[w][rw * 32 + col] = acc[r];
    }
    __syncthreads();

    float* dst = gpart + (size_t)(blockIdx.x & 7) * 2048 + (size_t)b * 1024;
    for (int e = tid; e < 1024; e += 256) {
        float s = red[0][e] + red[1][e] + red[2][e] + red[3][e];
        atomicAdd(&dst[e], s);
    }
}

// ---------------------------------------------------------------- k_attn ----
// grid = 2 (one block per batch), block = 1024.  thread = (n = tid>>5, m = tid&31)
__global__ __launch_bounds__(1024) void k_attn(const float* __restrict__ gpart,
                                               const float* __restrict__ gamma_p,
                                               float* __restrict__ M) {
    const int b   = blockIdx.x;
    const int tid = threadIdx.x;
    const int n   = tid >> 5;
    const int m   = tid & 31;

    float g = 0.f;
    #pragma unroll
    for (int s = 0; s < 8; ++s) g += gpart[(size_t)s * 2048 + (size_t)b * 1024 + tid];

    __shared__ float nrm[32];
    if (n == m) nrm[n] = fmaxf(sqrtf(g), EPSN);
    __syncthreads();

    float e = g / (nrm[n] * nrm[m]);   // cosine energy

    // row reductions within the 32-thread row group
    float rmax = e, rmin = e;
    #pragma unroll
    for (int off = 16; off > 0; off >>= 1) {
        rmax = fmaxf(rmax, __shfl_xor(rmax, off, 32));
        rmin = fminf(rmin, __shfl_xor(rmin, off, 32));
    }
    // softmax(rowmax - e) == exp(rmin - e) / sum(exp(rmin - e))
    float pv  = expf(rmin - e);
    float sum = pv;
    #pragma unroll
    for (int off = 16; off > 0; off >>= 1) sum += __shfl_xor(sum, off, 32);
    float a = pv / sum;

    float gm = gamma_p[0];
    M[(size_t)b * 1024 + tid] = gm * a + (n == m ? 1.f : 0.f);
}

// --------------------------------------------------------------- k_apply ----
// out = M @ q.  grid = 2048 blocks (1024/batch), block = 256.
// Thread owns one float4 d-group: 32 row loads -> 32 row outputs (1x R, 1x W).
__device__ __forceinline__ void fma4(float4& o, float c, const float4& a) {
    o.x += c * a.x; o.y += c * a.y; o.z += c * a.z; o.w += c * a.w;
}

__global__ __launch_bounds__(256) void k_apply(const float* __restrict__ x,
                                               const float* __restrict__ M,
                                               float* __restrict__ out) {
    __shared__ __align__(16) float Ml[1024];
    const int tid = threadIdx.x;
    const int b   = blockIdx.x >> 10;
    const float* Mb = M + (size_t)b * 1024;
    #pragma unroll
    for (int i = 0; i < 4; ++i) Ml[tid + i * 256] = Mb[tid + i * 256];
    __syncthreads();

    const size_t d4   = ((size_t)(blockIdx.x & 1023)) * 256 + tid; // 0..262143
    const size_t rs4  = D_FULL / 4;                                 // row stride in float4
    const float4* xb  = (const float4*)(x)   + (size_t)b * NROW * rs4;
    float4*       ob  = (float4*)(out)       + (size_t)b * NROW * rs4;

    float4 qv[32];
    #pragma unroll
    for (int m = 0; m < 32; ++m) qv[m] = xb[(size_t)m * rs4 + d4];

    for (int n = 0; n < 32; ++n) {
        const float4* Mr = (const float4*)(&Ml[n * 32]);
        float4 o = make_float4(0.f, 0.f, 0.f, 0.f);
        #pragma unroll
        for (int m4 = 0; m4 < 8; ++m4) {
            float4 c = Mr[m4];
            fma4(o, c.x, qv[m4 * 4 + 0]);
            fma4(o, c.y, qv[m4 * 4 + 1]);
            fma4(o, c.z, qv[m4 * 4 + 2]);
            fma4(o, c.w, qv[m4 * 4 + 3]);
        }
        ob[(size_t)n * rs4 + d4] = o;
    }
}

// ------------------------------------------------------------------ entry ---
extern "C" void kernel_launch(void* const* d_in, const int* in_sizes, int n_in,
                              void* d_out, int out_size, void* d_ws, size_t ws_size,
                              hipStream_t stream) {
    const float* x     = (const float*)d_in[0];
    const float* gamma = (const float*)d_in[1];
    float*       out   = (float*)d_out;
    float*       ws    = (float*)d_ws;

    float* gpart = ws;            // 8 slots * 2 batches * 1024 = 16384 floats
    float* Mws   = ws + 16384;    // 2 * 1024 floats

    k_zero <<<16,   256,  0, stream>>>(gpart);
    k_gram <<<512,  256,  0, stream>>>(x, gpart);
    k_attn <<<2,    1024, 0, stream>>>(gpart, gamma, Mws);
    k_apply<<<2048, 256,  0, stream>>>(x, Mws, out);
}

// Round 8
// 524.339 us; speedup vs baseline: 1.1366x; 1.1366x over previous
//
#include <hip/hip_runtime.h>

// LAM module: out = gamma * (softmax(rowmax(E)-E) @ q) + x,  E = cosine-sim(q,q)
// B=2, N=32, D = 64*128*128 = 1,048,576, all fp32.
//
//  k_zero : zero 8 partial-Gram slots in ws
//  k_gram : G[b] = q q^T via bf16 MFMA 32x32x16, LDS-staged coalesced loads
//  k_attn : tiny 32x32 softmax; M = gamma*attention + I  (folds residual)
//  k_apply: out = M @ q, nontemporal stores (preserve x in L3 for reads)

#define NROW 32
static const size_t D_FULL = 1048576ull;   // 64*128*128
#define EPSN 1e-12f

typedef __attribute__((ext_vector_type(8)))  __bf16 bf16x8;
typedef __attribute__((ext_vector_type(4)))  __bf16 bf16x4;
typedef __attribute__((ext_vector_type(16))) float  f32x16;
typedef __attribute__((ext_vector_type(4)))  float  f32x4;

// ---------------------------------------------------------------- k_zero ----
__global__ __launch_bounds__(256) void k_zero(float* g) {
    int i = blockIdx.x * 256 + threadIdx.x;
    ((float4*)g)[i] = make_float4(0.f, 0.f, 0.f, 0.f);
}

// ---------------------------------------------------------------- k_gram ----
// grid = 1024 blocks (512/batch), block = 256 (4 waves), 4 blocks/CU.
// Block owns 32 rows x 2048 cols, processed as 4 subtiles of 512 cols:
//   stage:  coalesced row sweeps (1 KB/instr from ONE row), fp32->bf16 -> LDS
//   mfma :  wave w does ksteps [w*8, w*8+8) of the subtile's 32 K-steps
// LDS row stride 520 bf16 (1040 B, 65*16): rows 16B-aligned AND the odd
// multiplier spreads the 32 b128-readers uniformly over the 8 quad-banks.
#define GSTRIDE 520
__global__ __launch_bounds__(256, 4) void k_gram(const float* __restrict__ x,
                                                 float* __restrict__ gpart) {
    __shared__ __align__(16) unsigned char smem[NROW * GSTRIDE * 2]; // 33280 B
    __bf16* tile = (__bf16*)smem;
    float (*red)[1024] = (float (*)[1024])smem;   // overlay, used after k-loop

    const int tid  = threadIdx.x;
    const int w    = tid >> 6;
    const int lane = tid & 63;
    const int b    = (int)(blockIdx.x >> 9);              // 0..1
    const size_t dblk = ((size_t)(blockIdx.x & 511)) * 2048;
    const int row  = lane & 31;
    const int kg   = lane >> 5;

    const float* xb = x + (size_t)b * NROW * D_FULL + dblk;
    const int srow0 = tid >> 7;        // 0/1: row parity this thread stages
    const int sc4   = tid & 127;       // float4 col within 512-col subtile

    f32x16 acc = (f32x16)(0.0f);

    for (int s = 0; s < 4; ++s) {
        __syncthreads();                       // prev subtile reads complete
        const float* src = xb + s * 512;
        #pragma unroll
        for (int sw = 0; sw < 16; ++sw) {
            int r = sw * 2 + srow0;
            float4 v = *(const float4*)(src + (size_t)r * D_FULL + sc4 * 4);
            bf16x4 h;
            h[0] = (__bf16)v.x; h[1] = (__bf16)v.y;
            h[2] = (__bf16)v.z; h[3] = (__bf16)v.w;
            *(bf16x4*)&tile[r * GSTRIDE + sc4 * 4] = h;
        }
        __syncthreads();
        #pragma unroll
        for (int kk = 0; kk < 8; ++kk) {
            int kstep = w * 8 + kk;
            bf16x8 f = *(const bf16x8*)&tile[row * GSTRIDE + kstep * 16 + kg * 8];
            acc = __builtin_amdgcn_mfma_f32_32x32x16_bf16(f, f, acc, 0, 0, 0);
        }
    }
    __syncthreads();   // all tile reads done before red overlays the tile

    // C/D layout (verified m74/m101): col = lane&31, row = (r&3)+8*(r>>2)+4*(lane>>5)
    const int col  = lane & 31;
    const int rsel = lane >> 5;
    #pragma unroll
    for (int r = 0; r < 16; ++r) {
        int rw = (r & 3) + 8 * (r >> 2) + 4 * rsel;
        red[w][rw * 32 + col] = acc[r];
    }
    __syncthreads();

    float* dst = gpart + (size_t)(blockIdx.x & 7) * 2048 + (size_t)b * 1024;
    for (int e = tid; e < 1024; e += 256) {
        float sum = red[0][e] + red[1][e] + red[2][e] + red[3][e];
        atomicAdd(&dst[e], sum);
    }
}

// ---------------------------------------------------------------- k_attn ----
__global__ __launch_bounds__(1024) void k_attn(const float* __restrict__ gpart,
                                               const float* __restrict__ gamma_p,
                                               float* __restrict__ M) {
    const int b   = blockIdx.x;
    const int tid = threadIdx.x;
    const int n   = tid >> 5;
    const int m   = tid & 31;

    float g = 0.f;
    #pragma unroll
    for (int s = 0; s < 8; ++s) g += gpart[(size_t)s * 2048 + (size_t)b * 1024 + tid];

    __shared__ float nrm[32];
    if (n == m) nrm[n] = fmaxf(sqrtf(g), EPSN);
    __syncthreads();

    float e = g / (nrm[n] * nrm[m]);

    float rmin = e;
    #pragma unroll
    for (int off = 16; off > 0; off >>= 1) rmin = fminf(rmin, __shfl_xor(rmin, off, 32));
    // softmax(rowmax - e) == exp(rmin - e) / sum(exp(rmin - e))
    float pv  = expf(rmin - e);
    float sum = pv;
    #pragma unroll
    for (int off = 16; off > 0; off >>= 1) sum += __shfl_xor(sum, off, 32);
    float a = pv / sum;

    M[(size_t)b * 1024 + tid] = gamma_p[0] * a + (n == m ? 1.f : 0.f);
}

// --------------------------------------------------------------- k_apply ----
// out = M @ q.  grid = 2048 blocks (1024/batch), block = 256.
// Thread owns one float4 d-group: 32 row loads -> 32 row outputs.
// Stores are NONTEMPORAL: out is never re-read; keeps x resident in L3 so
// the reads (warmed by k_gram) hit L3 instead of being evicted by our writes.
__device__ __forceinline__ void fma4(float4& o, float c, const float4& a) {
    o.x += c * a.x; o.y += c * a.y; o.z += c * a.z; o.w += c * a.w;
}

__global__ __launch_bounds__(256) void k_apply(const float* __restrict__ x,
                                               const float* __restrict__ M,
                                               float* __restrict__ out) {
    __shared__ __align__(16) float Ml[1024];
    const int tid = threadIdx.x;
    const int b   = blockIdx.x >> 10;
    const float* Mb = M + (size_t)b * 1024;
    #pragma unroll
    for (int i = 0; i < 4; ++i) Ml[tid + i * 256] = Mb[tid + i * 256];
    __syncthreads();

    const size_t d4  = ((size_t)(blockIdx.x & 1023)) * 256 + tid;
    const size_t rs4 = D_FULL / 4;
    const float4* xb = (const float4*)(x) + (size_t)b * NROW * rs4;
    f32x4*        ob = (f32x4*)(out)      + (size_t)b * NROW * rs4;

    float4 qv[32];
    #pragma unroll
    for (int m = 0; m < 32; ++m) qv[m] = xb[(size_t)m * rs4 + d4];

    for (int n = 0; n < 32; ++n) {
        const float4* Mr = (const float4*)(&Ml[n * 32]);
        float4 o = make_float4(0.f, 0.f, 0.f, 0.f);
        #pragma unroll
        for (int m4 = 0; m4 < 8; ++m4) {
            float4 c = Mr[m4];
            fma4(o, c.x, qv[m4 * 4 + 0]);
            fma4(o, c.y, qv[m4 * 4 + 1]);
            fma4(o, c.z, qv[m4 * 4 + 2]);
            fma4(o, c.w, qv[m4 * 4 + 3]);
        }
        f32x4 ov; ov[0] = o.x; ov[1] = o.y; ov[2] = o.z; ov[3] = o.w;
        __builtin_nontemporal_store(ov, &ob[(size_t)n * rs4 + d4]);
    }
}

// ------------------------------------------------------------------ entry ---
extern "C" void kernel_launch(void* const* d_in, const int* in_sizes, int n_in,
                              void* d_out, int out_size, void* d_ws, size_t ws_size,
                              hipStream_t stream) {
    const float* x     = (const float*)d_in[0];
    const float* gamma = (const float*)d_in[1];
    float*       out   = (float*)d_out;
    float*       ws    = (float*)d_ws;

    float* gpart = ws;            // 8 slots * 2 batches * 1024 = 16384 floats
    float* Mws   = ws + 16384;    // 2 * 1024 floats

    k_zero <<<16,   256,  0, stream>>>(gpart);
    k_gram <<<1024, 256,  0, stream>>>(x, gpart);
    k_attn <<<2,    1024, 0, stream>>>(gpart, gamma, Mws);
    k_apply<<<2048, 256,  0, stream>>>(x, Mws, out);
}